// Round 1
// baseline (480.217 us; speedup 1.0000x reference)
//
#include <hip/hip_runtime.h>
#include <hip/hip_bf16.h>

#define N_TOTAL   131072
#define D         512
#define D_ATT     256
#define N_HEAD    4
#define N_CLASSES 53
#define BAG       16
#define M_TILE    128
#define BK        64
#define BAGS_PER_BLK (M_TILE / BAG)   // 8
#define THREADS   512
#define N_BLOCKS  (N_TOTAL / M_TILE)  // 1024

typedef __attribute__((ext_vector_type(8))) short bf16x8;
typedef __attribute__((ext_vector_type(4))) float f32x4;

__device__ __forceinline__ unsigned short f2bf(float f) {
    __hip_bfloat16 h = __float2bfloat16(f);
    return *reinterpret_cast<unsigned short*>(&h);
}
__device__ __forceinline__ float bfbits2f(unsigned int lo16) {
    unsigned int v = lo16 << 16;
    return __uint_as_float(v);
}
__device__ __forceinline__ float bfhi2f(unsigned int hibits) {
    return __uint_as_float(hibits & 0xffff0000u);
}

// Prep: W1 [512][256] f32 -> W1T bf16 [256][512] ; Wc [512][53] -> WcT f32 [53][512]
__global__ void prep_kernel(const float* __restrict__ W1, const float* __restrict__ Wc,
                            unsigned short* __restrict__ W1T, float* __restrict__ WcT) {
    int tid = blockIdx.x * 256 + threadIdx.x;
    if (tid < D * D_ATT) {
        int k = tid >> 8;        // 0..511
        int n = tid & 255;       // 0..255
        W1T[n * D + k] = f2bf(W1[k * D_ATT + n]);
    } else {
        int t2 = tid - D * D_ATT;
        if (t2 < D * N_CLASSES) {
            int k = t2 / N_CLASSES;
            int c = t2 - k * N_CLASSES;
            WcT[c * D + k] = Wc[k * N_CLASSES + c];
        }
    }
}

// LDS layout constants
#define LDA 72     // ldsA row stride in bf16 (64 + 8 pad)
#define LDB 72     // ldsB row stride in bf16
#define LDH 258    // ldsH row stride in bf16 (256 + 2 pad) -> 516B = 129 words, odd mod 32
#define LDR 516    // ldsR row stride in floats (512 + 4 pad)

__global__ void __launch_bounds__(THREADS)
fused_kernel(const float* __restrict__ x,
             const unsigned short* __restrict__ W1T,   // bf16 bits [256][512]
             const float* __restrict__ W2,             // [256][4]
             const float* __restrict__ WcT,            // [53][512]
             const float* __restrict__ bc,             // [53]
             float* __restrict__ out)                  // [8192][53]
{
    // union region: staging (A 18432 + B 36864 = 55296) | H (66048) | R (16512)
    __shared__ __align__(16) unsigned char lds_u[66048];
    __shared__ float ldsW2T[N_HEAD * D_ATT];   // transposed W2: [head][n]
    __shared__ float ldsS[M_TILE * N_HEAD];
    __shared__ float ldsM[BAGS_PER_BLK * N_HEAD];
    __shared__ float ldsDen[BAGS_PER_BLK * N_HEAD];
    __shared__ float ldsW[M_TILE];

    unsigned short* ldsA = (unsigned short*)lds_u;            // [128][LDA]
    unsigned short* ldsB = (unsigned short*)(lds_u + 18432);  // [256][LDB]
    unsigned short* ldsH = (unsigned short*)lds_u;            // [128][LDH]
    float*          ldsR = (float*)lds_u;                     // [8][LDR]

    const int tid  = threadIdx.x;
    const int wave = tid >> 6;
    const int lane = tid & 63;
    const int quad = lane >> 4;
    const int l16  = lane & 15;
    const int wr   = (wave & 1) * 64;   // row offset of wave tile
    const int wc2  = (wave >> 1) * 64;  // col offset of wave tile
    const int row_base = blockIdx.x * M_TILE;

    // preload W2 transposed into LDS
    for (int i = tid; i < D_ATT * N_HEAD; i += THREADS) {
        int n = i >> 2, h = i & 3;
        ldsW2T[h * D_ATT + n] = W2[i];
    }

    f32x4 acc[4][4] = {};

    // ---- K loop: X(128xK) @ W1(KxD_ATT), bf16 MFMA ----
    for (int kt = 0; kt < D / BK; ++kt) {
        // stage A: x[row_base..+127][kt*64..+63] f32 -> bf16 LDS
        #pragma unroll
        for (int i = 0; i < 4; ++i) {
            int f  = i * THREADS + tid;       // 0..2047 float4 chunks
            int r  = f >> 4;                  // row 0..127
            int kc = (f & 15) << 2;           // 0..60
            const float4 v = *reinterpret_cast<const float4*>(
                &x[(size_t)(row_base + r) * D + kt * BK + kc]);
            unsigned int p0 = (unsigned int)f2bf(v.x) | ((unsigned int)f2bf(v.y) << 16);
            unsigned int p1 = (unsigned int)f2bf(v.z) | ((unsigned int)f2bf(v.w) << 16);
            uint2 p; p.x = p0; p.y = p1;
            *reinterpret_cast<uint2*>(&ldsA[r * LDA + kc]) = p;
        }
        // stage B: W1T[256][kt*64..+63] bf16
        #pragma unroll
        for (int i = 0; i < 4; ++i) {
            int cdx = i * THREADS + tid;      // 0..2047 chunks of 8 bf16
            int r   = cdx >> 3;               // n row 0..255
            int kc  = (cdx & 7) << 3;         // 0..56
            uint4 v = *reinterpret_cast<const uint4*>(&W1T[(size_t)r * D + kt * BK + kc]);
            *reinterpret_cast<uint4*>(&ldsB[r * LDB + kc]) = v;
        }
        __syncthreads();

        #pragma unroll
        for (int kk = 0; kk < 2; ++kk) {
            const int kb = kk * 32 + quad * 8;
            bf16x8 af[4], bfr[4];
            #pragma unroll
            for (int mi = 0; mi < 4; ++mi)
                af[mi] = *reinterpret_cast<const bf16x8*>(&ldsA[(wr + mi * 16 + l16) * LDA + kb]);
            #pragma unroll
            for (int ni = 0; ni < 4; ++ni)
                bfr[ni] = *reinterpret_cast<const bf16x8*>(&ldsB[(wc2 + ni * 16 + l16) * LDB + kb]);
            #pragma unroll
            for (int mi = 0; mi < 4; ++mi)
                #pragma unroll
                for (int ni = 0; ni < 4; ++ni)
                    acc[mi][ni] = __builtin_amdgcn_mfma_f32_16x16x32_bf16(
                        af[mi], bfr[ni], acc[mi][ni], 0, 0, 0);
        }
        __syncthreads();
    }

    // ---- epilogue 1: tanh, write H (bf16) to LDS ----
    #pragma unroll
    for (int mi = 0; mi < 4; ++mi) {
        #pragma unroll
        for (int ni = 0; ni < 4; ++ni) {
            f32x4 v = acc[mi][ni];
            #pragma unroll
            for (int r = 0; r < 4; ++r) {
                float e = __expf(2.f * v[r]);
                float t = 1.f - 2.f / (e + 1.f);   // tanh
                int row = wr + mi * 16 + quad * 4 + r;
                int col = wc2 + ni * 16 + l16;
                ldsH[row * LDH + col] = f2bf(t);
            }
        }
    }
    __syncthreads();

    // ---- epilogue 2: s[row][head] = sum_n H[row][n] * W2[n][head] ----
    {
        const int row  = tid >> 2;          // 0..127
        const int head = tid & 3;
        const unsigned short* hrow = &ldsH[row * LDH];
        const float* w2h = &ldsW2T[head * D_ATT];
        float s = 0.f;
        #pragma unroll 8
        for (int j = 0; j < 64; ++j) {
            uint2 u = *reinterpret_cast<const uint2*>(&hrow[j * 4]);
            float4 wv = *reinterpret_cast<const float4*>(&w2h[j * 4]);
            s += bfbits2f(u.x & 0xffffu) * wv.x + bfhi2f(u.x) * wv.y
               + bfbits2f(u.y & 0xffffu) * wv.z + bfhi2f(u.y) * wv.w;
        }
        ldsS[row * 4 + head] = s;
    }
    __syncthreads();

    // ---- epilogue 3: per-bag per-head softmax stats ----
    if (tid < BAGS_PER_BLK * N_HEAD) {        // 32 threads
        int bag = tid >> 2, head = tid & 3;
        float m = -1e30f;
        for (int i = 0; i < BAG; ++i)
            m = fmaxf(m, ldsS[(bag * BAG + i) * 4 + head]);
        float den = 0.f;
        for (int i = 0; i < BAG; ++i)
            den += __expf(ldsS[(bag * BAG + i) * 4 + head] - m);
        ldsM[tid] = m;
        ldsDen[tid] = 1.f / den;
    }
    __syncthreads();
    if (tid < M_TILE) {                        // 128 threads: w[row]
        int row = tid, bag = row >> 4;
        float w = 0.f;
        #pragma unroll
        for (int h = 0; h < 4; ++h)
            w += __expf(ldsS[row * 4 + h] - ldsM[bag * 4 + h]) * ldsDen[bag * 4 + h];
        ldsW[row] = 0.25f * w;
    }
    __syncthreads();

    // ---- epilogue 4: bag_repr[b][d] = sum_i w * x  (one wave per bag) ----
    {
        const int b  = tid >> 6;              // 0..7
        const int dc = (tid & 63) * 8;        // 0..504
        float4 r0 = {0.f, 0.f, 0.f, 0.f}, r1 = {0.f, 0.f, 0.f, 0.f};
        for (int i = 0; i < BAG; ++i) {
            int row = b * BAG + i;
            float wv = ldsW[row];
            const float4* xp = reinterpret_cast<const float4*>(
                &x[(size_t)(row_base + row) * D + dc]);
            float4 a = xp[0], c = xp[1];
            r0.x += wv * a.x; r0.y += wv * a.y; r0.z += wv * a.z; r0.w += wv * a.w;
            r1.x += wv * c.x; r1.y += wv * c.y; r1.z += wv * c.z; r1.w += wv * c.w;
        }
        *reinterpret_cast<float4*>(&ldsR[b * LDR + dc])     = r0;
        *reinterpret_cast<float4*>(&ldsR[b * LDR + dc + 4]) = r1;
    }
    __syncthreads();

    // ---- epilogue 5: logits[b][c] = bag_repr[b] . WcT[c] + bc[c] ----
    if (tid < 448) {
        int c = tid >> 3;          // 0..55
        int b = tid & 7;
        if (c < N_CLASSES) {
            float a = bc[c];
            const float4* rp = reinterpret_cast<const float4*>(&ldsR[b * LDR]);
            const float4* wp = reinterpret_cast<const float4*>(&WcT[(size_t)c * D]);
            #pragma unroll 8
            for (int j = 0; j < D / 4; ++j) {
                float4 r = rp[j], w = wp[j];
                a += r.x * w.x + r.y * w.y + r.z * w.z + r.w * w.w;
            }
            out[((size_t)blockIdx.x * BAGS_PER_BLK + b) * N_CLASSES + c] = a;
        }
    }
}

extern "C" void kernel_launch(void* const* d_in, const int* in_sizes, int n_in,
                              void* d_out, int out_size, void* d_ws, size_t ws_size,
                              hipStream_t stream) {
    const float* x  = (const float*)d_in[0];
    const float* W1 = (const float*)d_in[1];
    const float* W2 = (const float*)d_in[2];
    const float* Wc = (const float*)d_in[3];
    const float* bc = (const float*)d_in[4];
    // d_in[5] seg_ids, d_in[6] n_bags: unused (uniform bags of 16)

    unsigned short* W1T = (unsigned short*)d_ws;                       // 262144 B
    float*          WcT = (float*)((char*)d_ws + (size_t)D * D_ATT * 2); // 108544 B

    int prep_total = D * D_ATT + D * N_CLASSES;   // 158208
    prep_kernel<<<dim3((prep_total + 255) / 256), dim3(256), 0, stream>>>(W1, Wc, W1T, WcT);

    fused_kernel<<<dim3(N_BLOCKS), dim3(THREADS), 0, stream>>>(
        x, W1T, W2, WcT, bc, (float*)d_out);
}

// Round 2
// 476.379 us; speedup vs baseline: 1.0081x; 1.0081x over previous
//
#include <hip/hip_runtime.h>
#include <hip/hip_bf16.h>

#define N_TOTAL   131072
#define D         512
#define D_ATT     256
#define N_HEAD    4
#define N_CLASSES 53
#define BAG       16
#define M_TILE    64
#define BAGS_PER_BLK (M_TILE / BAG)   // 4
#define THREADS   256
#define N_BLOCKS  (N_TOTAL / M_TILE)  // 2048

typedef __attribute__((ext_vector_type(8))) short bf16x8;
typedef __attribute__((ext_vector_type(4))) float f32x4;

__device__ __forceinline__ unsigned short f2bf(float f) {
    __hip_bfloat16 h = __float2bfloat16(f);
    return *reinterpret_cast<unsigned short*>(&h);
}
__device__ __forceinline__ float bfbits2f(unsigned int lo16) {
    return __uint_as_float(lo16 << 16);
}
__device__ __forceinline__ float bfhi2f(unsigned int hibits) {
    return __uint_as_float(hibits & 0xffff0000u);
}

// Prep: W1 [512][256] f32 -> W1T bf16 [256][512] ; Wc [512][53] -> WcT f32 [53][512]
__global__ void prep_kernel(const float* __restrict__ W1, const float* __restrict__ Wc,
                            unsigned short* __restrict__ W1T, float* __restrict__ WcT) {
    int tid = blockIdx.x * 256 + threadIdx.x;
    if (tid < D * D_ATT) {
        int k = tid >> 8;
        int n = tid & 255;
        W1T[n * D + k] = f2bf(W1[k * D_ATT + n]);
    } else {
        int t2 = tid - D * D_ATT;
        if (t2 < D * N_CLASSES) {
            int k = t2 / N_CLASSES;
            int c = t2 - k * N_CLASSES;
            WcT[c * D + k] = Wc[k * N_CLASSES + c];
        }
    }
}

#define LDX 520    // ldsX row stride in bf16 (512 + 8)  -> 1040 B, 260 words (mod 32 = 4)
#define LDH 260    // ldsH row stride in bf16 (256 + 4)  -> 520 B (8B aligned rows)
#define LDR 516    // ldsR row stride in floats

__global__ void __launch_bounds__(THREADS)
fused_kernel(const float* __restrict__ x,
             const unsigned short* __restrict__ W1T,   // bf16 bits [256][512]
             const float* __restrict__ W2,             // [256][4]
             const float* __restrict__ WcT,            // [53][512]
             const float* __restrict__ bc,             // [53]
             float* __restrict__ out)                  // [8192][53]
{
    // X region 64*520*2 = 66560 B; after GEMM it is reused:
    //   H at offset 0       : 64*260*2 = 33280 B
    //   R at offset 33280   : 4*516*4 =  8256 B
    __shared__ __align__(16) unsigned char lds_u[66560];
    __shared__ float ldsW2T[N_HEAD * D_ATT];   // [head][n]
    __shared__ float ldsS[M_TILE * N_HEAD];
    __shared__ float ldsM[BAGS_PER_BLK * N_HEAD];
    __shared__ float ldsDen[BAGS_PER_BLK * N_HEAD];
    __shared__ float ldsW[M_TILE];

    unsigned short* ldsX = (unsigned short*)lds_u;            // [64][LDX]
    unsigned short* ldsH = (unsigned short*)lds_u;            // [64][LDH]
    float*          ldsR = (float*)(lds_u + 33280);           // [4][LDR]

    const int tid  = threadIdx.x;
    const int wave = tid >> 6;          // 0..3, each wave: 64 rows x 64 cols
    const int lane = tid & 63;
    const int quad = lane >> 4;
    const int l16  = lane & 15;
    const int wc2  = wave * 64;         // col offset of wave tile
    const int row_base = blockIdx.x * M_TILE;

    // preload W2 transposed into LDS
    for (int i = tid; i < D_ATT * N_HEAD; i += THREADS) {
        int n = i >> 2, h = i & 3;
        ldsW2T[h * D_ATT + n] = W2[i];
    }

    // ---- stage whole X tile (64 x 512) to bf16 LDS, once ----
    // 8192 float4 chunks / 256 threads = 32 per thread, row-contiguous per wave.
    {
        const float* xb = &x[(size_t)row_base * D];
        #pragma unroll 8
        for (int i = 0; i < 32; ++i) {
            int f  = i * THREADS + tid;       // 0..8191
            int r  = f >> 7;                  // row 0..63
            int c4 = f & 127;                 // float4 index in row
            float4 v = *reinterpret_cast<const float4*>(&xb[(size_t)r * D + c4 * 4]);
            unsigned int p0 = (unsigned int)f2bf(v.x) | ((unsigned int)f2bf(v.y) << 16);
            unsigned int p1 = (unsigned int)f2bf(v.z) | ((unsigned int)f2bf(v.w) << 16);
            uint2 p; p.x = p0; p.y = p1;
            *reinterpret_cast<uint2*>(&ldsX[r * LDX + c4 * 4]) = p;
        }
    }
    __syncthreads();

    // ---- barrier-free K loop: acc(64x64) += X(64xK) @ W1T^T(Kx64) ----
    f32x4 acc[4][4] = {};
    {
        const unsigned short* Wb = &W1T[(size_t)wc2 * D];   // wave's 64 B-rows
        bf16x8 a0[4], b0[4], a1[4], b1[4];

        #define LOAD_A(ks, dst)                                                        \
            { int kb = (ks) * 32 + quad * 8;                                           \
              _Pragma("unroll")                                                        \
              for (int mi = 0; mi < 4; ++mi)                                           \
                  dst[mi] = *reinterpret_cast<const bf16x8*>(                          \
                      &ldsX[(mi * 16 + l16) * LDX + kb]); }
        #define LOAD_B(ks, dst)                                                        \
            { int kb = (ks) * 32 + quad * 8;                                           \
              _Pragma("unroll")                                                        \
              for (int ni = 0; ni < 4; ++ni)                                           \
                  dst[ni] = *reinterpret_cast<const bf16x8*>(                          \
                      &Wb[(size_t)(ni * 16 + l16) * D + kb]); }
        #define MFMA(af, bfr)                                                          \
            { _Pragma("unroll")                                                        \
              for (int mi = 0; mi < 4; ++mi)                                           \
                  _Pragma("unroll")                                                    \
                  for (int ni = 0; ni < 4; ++ni)                                       \
                      acc[mi][ni] = __builtin_amdgcn_mfma_f32_16x16x32_bf16(           \
                          af[mi], bfr[ni], acc[mi][ni], 0, 0, 0); }

        LOAD_A(0, a0); LOAD_B(0, b0);
        #pragma unroll
        for (int ks = 0; ks < 16; ks += 2) {
            LOAD_A(ks + 1, a1); LOAD_B(ks + 1, b1);
            MFMA(a0, b0);
            if (ks + 2 < 16) { LOAD_A(ks + 2, a0); LOAD_B(ks + 2, b0); }
            MFMA(a1, b1);
        }
        #undef LOAD_A
        #undef LOAD_B
        #undef MFMA
    }
    __syncthreads();   // all waves done reading ldsX; H may overwrite

    // ---- epilogue 1: tanh, write H (bf16) over X region ----
    #pragma unroll
    for (int mi = 0; mi < 4; ++mi) {
        #pragma unroll
        for (int ni = 0; ni < 4; ++ni) {
            f32x4 v = acc[mi][ni];
            #pragma unroll
            for (int r = 0; r < 4; ++r) {
                float e = __expf(2.f * v[r]);
                float t = 1.f - 2.f / (e + 1.f);   // tanh
                int row = mi * 16 + quad * 4 + r;  // C-layout: row=quad*4+reg
                int col = wc2 + ni * 16 + l16;     //           col=lane&15
                ldsH[row * LDH + col] = f2bf(t);
            }
        }
    }
    __syncthreads();

    // ---- epilogue 2: s[row][head] = sum_n H[row][n] * W2[n][head] ----
    {
        const int row  = tid >> 2;          // 0..63
        const int head = tid & 3;
        const unsigned short* hrow = &ldsH[row * LDH];
        const float* w2h = &ldsW2T[head * D_ATT];
        float s = 0.f;
        #pragma unroll 8
        for (int j = 0; j < 64; ++j) {
            uint2 u = *reinterpret_cast<const uint2*>(&hrow[j * 4]);
            float4 wv = *reinterpret_cast<const float4*>(&w2h[j * 4]);
            s += bfbits2f(u.x & 0xffffu) * wv.x + bfhi2f(u.x) * wv.y
               + bfbits2f(u.y & 0xffffu) * wv.z + bfhi2f(u.y) * wv.w;
        }
        ldsS[row * 4 + head] = s;
    }
    __syncthreads();

    // ---- epilogue 3: per-bag per-head softmax stats ----
    if (tid < BAGS_PER_BLK * N_HEAD) {        // 16 threads
        int bag = tid >> 2, head = tid & 3;
        float m = -1e30f;
        for (int i = 0; i < BAG; ++i)
            m = fmaxf(m, ldsS[(bag * BAG + i) * 4 + head]);
        float den = 0.f;
        for (int i = 0; i < BAG; ++i)
            den += __expf(ldsS[(bag * BAG + i) * 4 + head] - m);
        ldsM[tid] = m;
        ldsDen[tid] = 1.f / den;
    }
    __syncthreads();
    if (tid < M_TILE) {                        // 64 threads: w[row]
        int row = tid, bag = row >> 4;
        float w = 0.f;
        #pragma unroll
        for (int h = 0; h < 4; ++h)
            w += __expf(ldsS[row * 4 + h] - ldsM[bag * 4 + h]) * ldsDen[bag * 4 + h];
        ldsW[row] = 0.25f * w;
    }
    __syncthreads();

    // ---- epilogue 4: bag_repr[b][d] = sum_i w * x  (one wave per bag, x from L2) ----
    {
        const int b  = wave;                  // 0..3
        const int dc = lane * 8;              // 0..504
        float4 r0 = {0.f, 0.f, 0.f, 0.f}, r1 = {0.f, 0.f, 0.f, 0.f};
        for (int i = 0; i < BAG; ++i) {
            int row = b * BAG + i;
            float wv = ldsW[row];
            const float4* xp = reinterpret_cast<const float4*>(
                &x[(size_t)(row_base + row) * D + dc]);
            float4 a = xp[0], c = xp[1];
            r0.x += wv * a.x; r0.y += wv * a.y; r0.z += wv * a.z; r0.w += wv * a.w;
            r1.x += wv * c.x; r1.y += wv * c.y; r1.z += wv * c.z; r1.w += wv * c.w;
        }
        *reinterpret_cast<float4*>(&ldsR[b * LDR + dc])     = r0;
        *reinterpret_cast<float4*>(&ldsR[b * LDR + dc + 4]) = r1;
    }
    __syncthreads();

    // ---- epilogue 5: logits[b][c] = bag_repr[b] . WcT[c] + bc[c] ----
    {
        int c = tid >> 2;          // 0..63
        int b = tid & 3;
        if (c < N_CLASSES) {
            float a = bc[c];
            const float4* rp = reinterpret_cast<const float4*>(&ldsR[b * LDR]);
            const float4* wp = reinterpret_cast<const float4*>(&WcT[(size_t)c * D]);
            #pragma unroll 8
            for (int j = 0; j < D / 4; ++j) {
                float4 r = rp[j], w = wp[j];
                a += r.x * w.x + r.y * w.y + r.z * w.z + r.w * w.w;
            }
            out[((size_t)blockIdx.x * BAGS_PER_BLK + b) * N_CLASSES + c] = a;
        }
    }
}

extern "C" void kernel_launch(void* const* d_in, const int* in_sizes, int n_in,
                              void* d_out, int out_size, void* d_ws, size_t ws_size,
                              hipStream_t stream) {
    const float* x  = (const float*)d_in[0];
    const float* W1 = (const float*)d_in[1];
    const float* W2 = (const float*)d_in[2];
    const float* Wc = (const float*)d_in[3];
    const float* bc = (const float*)d_in[4];

    unsigned short* W1T = (unsigned short*)d_ws;
    float*          WcT = (float*)((char*)d_ws + (size_t)D * D_ATT * 2);

    int prep_total = D * D_ATT + D * N_CLASSES;
    prep_kernel<<<dim3((prep_total + 255) / 256), dim3(256), 0, stream>>>(W1, Wc, W1T, WcT);

    fused_kernel<<<dim3(N_BLOCKS), dim3(THREADS), 0, stream>>>(
        x, W1T, W2, WcT, bc, (float*)d_out);
}